// Round 14
// baseline (104.524 us; speedup 1.0000x reference)
//
#include <hip/hip_runtime.h>

// Chamfer distance: B=8, N=M=8192, D=3, fp32, via bf16 split-precision MFMA.
// R21: R20 post-mortem: one-pass main ran 61-73us (worse than 41us two-pass)
//   with MfmaUtil 10%. Added per phase: 2 global stores whose data regs
//   (cm0/cm1) are re-initialized next phase -> WAR on in-flight store ->
//   compiler vmcnt-drains stores every phase, and loads share vmcnt ->
//   depth-3 load pipeline poisoned (~2500 cyc/phase vs 774).
//   Fix: col-mins never touch the vmcnt domain in-loop. Per phase each
//   lane ds_writes its half-row col partial to a 64KB colsm LDS buffer
//   (lgkmcnt, cheap; no shfl — halves merged at dump). After the loop:
//   one coalesced 32KB dump/block to colpart (min of halves), then LDS is
//   reused as the row-combine cbuf (48KB < 64KB union).
//   Loop body = R19-proven FOLD + depth-3 rotation, zero stores in-loop.
//   Geometry: grid (8 b, 64 yb), 4 waves x m-quarter, 32 phases.
//   colreduce + prep_gt + fallback unchanged from R20.

#define B_DIM 8
#define N_DIM 8192
#define MT    (N_DIM / 32)      // 256 m-tiles per b
#define BLOCK 256
#define PPW   4                 // n-tiles per block (shared by all waves)

typedef short  bf16x8 __attribute__((ext_vector_type(8)));
typedef float  f32x16 __attribute__((ext_vector_type(16)));

__device__ __forceinline__ unsigned short bf16_rne(float f) {
    unsigned int u = __float_as_uint(f);
    u += 0x7fffu + ((u >> 16) & 1u);
    return (unsigned short)(u >> 16);
}
__device__ __forceinline__ float bf16f(unsigned short h) {
    return __uint_as_float(((unsigned int)h) << 16);
}

// ---------------- one-pass path ------------------------------------------
__global__ __launch_bounds__(256) void prep_gt(
    const float* __restrict__ gt, unsigned short* __restrict__ gtpack,
    float* __restrict__ out)
{
    const int i = blockIdx.x * 256 + threadIdx.x;    // 0 .. B*N-1
    if (i == 0) out[0] = 0.0f;
    const float x = gt[3*i+0], y = gt[3*i+1], z = gt[3*i+2];
    const unsigned short hx = bf16_rne(x), hy = bf16_rne(y), hz = bf16_rne(z);
    const unsigned short lx = bf16_rne(x - bf16f(hx));
    const unsigned short ly = bf16_rne(y - bf16f(hy));
    const unsigned short lz = bf16_rne(z - bf16f(hz));
    const float gn = x*x + y*y + z*z;
    const unsigned short gnh = bf16_rne(gn), gnl = bf16_rne(gn - bf16f(gnh));
    const unsigned short one = 0x3F80;

    const int b  = i >> 13, m = i & (N_DIM - 1);
    const int mt = m >> 5,  c = m & 31;
    unsigned short* p0 = gtpack + ((size_t)(b * MT + mt) * 64 + c) * 8;
    unsigned short* p1 = p0 + 32 * 8;
    bf16x8 h0 = {(short)hx,(short)hy,(short)hz,(short)lx,(short)ly,(short)lz,(short)hx,(short)hy};
    bf16x8 h1 = {(short)hz,(short)one,(short)one,(short)gnh,(short)gnl,0,0,0};
    *(bf16x8*)p0 = h0;
    *(bf16x8*)p1 = h1;
}

__global__ __launch_bounds__(BLOCK, 2) void chamfer_main(
    const float* __restrict__ pred, const bf16x8* __restrict__ gtpack,
    float* __restrict__ colpart, float* __restrict__ out)
{
    // 64 KB union: colsm[w][ph][tile][64] during loop -> dump -> cbuf.
    __shared__ float smem[16384];
    const int b    = blockIdx.x;            // XCD = b%8 -> per-b L2 locality
    const int yb   = blockIdx.y;
    const int w    = threadIdx.x >> 6, lane = threadIdx.x & 63;
    const int halfk = lane >> 5,  col = lane & 31;

    // A fragments: block's 4 n-tiles (shared by all waves).
    const float* srcb = pred + (size_t)b * N_DIM * 3;
    bf16x8 afrag[PPW];
    #pragma unroll
    for (int p = 0; p < PPW; ++p) {
        const int n = (yb * 4 + p) * 32 + col;
        const float x = srcb[3*n+0], y = srcb[3*n+1], z = srcb[3*n+2];
        const float ax = -2.f*x, ay = -2.f*y, az = -2.f*z;
        const unsigned short ahx = bf16_rne(ax), ahy = bf16_rne(ay), ahz = bf16_rne(az);
        const unsigned short alx = bf16_rne(ax - bf16f(ahx));
        const unsigned short aly = bf16_rne(ay - bf16f(ahy));
        const unsigned short alz = bf16_rne(az - bf16f(alz*0.f + az));  // == bf16_rne(az - bf16f(ahz))
        const float pn = x*x + y*y + z*z;
        const unsigned short pnh = bf16_rne(pn), pnl = bf16_rne(pn - bf16f(pnh));
        const unsigned short one = 0x3F80;
        const unsigned short alz2 = bf16_rne(az - bf16f(ahz));
        bf16x8 a0 = {(short)ahx,(short)ahy,(short)ahz,(short)ahx,(short)ahy,(short)ahz,(short)alx,(short)aly};
        bf16x8 a1 = {(short)alz2,(short)pnh,(short)pnl,(short)one,(short)one,0,0,0};
        afrag[p] = (halfk == 0) ? a0 : a1;
        (void)alz;
    }

    float best[PPW][16];
    #pragma unroll
    for (int p = 0; p < PPW; ++p)
        #pragma unroll
        for (int r = 0; r < 16; ++r) best[p][r] = 1e30f;

    // Wave w streams m-quarter w: 64 m-tiles from gtpack.
    const bf16x8* bw = gtpack + (size_t)b * (MT * 64) + (size_t)(w * 64) * 64 + lane;
    float* colsm = smem + w * 4096;         // this wave's 16 KB col region
    int ph = 0;

    // FOLDC: R19-proven FOLD (asm MFMA pair, s_nop 7/3 in-asm, min3 "+v")
    // + per-lane col partials -> ds_write (lgkmcnt only; NO vmcnt in loop).
#define FOLDC(c0_, c1_) { \
        float cm0 = 1e30f, cm1 = 1e30f; \
        _Pragma("unroll") \
        for (int p = 0; p < PPW; ++p) { \
            f32x16 d0, d1; \
            asm volatile( \
                "v_mfma_f32_32x32x16_bf16 %0, %2, %3, 0\n\t" \
                "v_mfma_f32_32x32x16_bf16 %1, %2, %4, 0\n\t" \
                "s_nop 7\n\t" \
                "s_nop 3" \
                : "=&v"(d0), "=&v"(d1) \
                : "v"(afrag[p]), "v"(c0_), "v"(c1_)); \
            __builtin_amdgcn_sched_barrier(0x34); \
            _Pragma("unroll") \
            for (int r = 0; r < 16; ++r) \
                asm("v_min3_f32 %0, %0, %1, %2" \
                    : "+v"(best[p][r]) : "v"(d0[r]), "v"(d1[r])); \
            _Pragma("unroll") \
            for (int r = 0; r < 16; r += 2) { \
                asm("v_min3_f32 %0, %0, %1, %2" \
                    : "+v"(cm0) : "v"(d0[r]), "v"(d0[r+1])); \
                asm("v_min3_f32 %0, %0, %1, %2" \
                    : "+v"(cm1) : "v"(d1[r]), "v"(d1[r+1])); \
            } \
        } \
        colsm[ph * 128 + lane]      = cm0;  /* tile0 half-partials */ \
        colsm[ph * 128 + 64 + lane] = cm1;  /* tile1 half-partials */ \
        ++ph; \
    }

    // Depth-3 rotation over 32 phases (R19 pattern).
    bf16x8 cA0 = bw[0],   cA1 = bw[64];
    bf16x8 cB0 = bw[128], cB1 = bw[192];
    bf16x8 cC0 = bw[256], cC1 = bw[320];
    bf16x8 cD0 = bw[384], cD1 = bw[448];
    bw += 512;
    for (int t = 0; t < 7; ++t) {
        FOLDC(cA0, cA1);  cA0 = bw[0];   cA1 = bw[64];
        FOLDC(cB0, cB1);  cB0 = bw[128]; cB1 = bw[192];
        FOLDC(cC0, cC1);  cC0 = bw[256]; cC1 = bw[320];
        FOLDC(cD0, cD1);  cD0 = bw[384]; cD1 = bw[448];
        bw += 512;
    }
    FOLDC(cA0, cA1);
    FOLDC(cB0, cB1);
    FOLDC(cC0, cC1);
    FOLDC(cD0, cD1);

    // ---- col dump: merge row-halves, coalesced store to colpart --------
    __syncthreads();
    {
        float* cpb = colpart + (size_t)(b * 64 + yb) * N_DIM;
        #pragma unroll
        for (int k = 0; k < 32; ++k) {
            const int m  = k * 256 + threadIdx.x;
            const int ww = m >> 11, p2 = (m >> 6) & 31;
            const int tl = (m >> 5) & 1, c = m & 31;
            const int base = ww * 4096 + p2 * 128 + tl * 64 + c;
            cpb[m] = fminf(smem[base], smem[base + 32]);
        }
    }
    __syncthreads();

    // ---- row-combine (reuse smem as cbuf): waves 1..3 export, wave 0
    // min-folds (same 128 n, disjoint m) then lane-reduces. -------------
    if (w > 0) {
        #pragma unroll
        for (int p = 0; p < PPW; ++p)
            #pragma unroll
            for (int r = 0; r < 16; ++r)
                smem[((w - 1) * 64 + p * 16 + r) * 64 + lane] = best[p][r];
    }
    __syncthreads();
    if (w == 0) {
        float bsum = 0.f;
        #pragma unroll
        for (int p = 0; p < PPW; ++p) {
            float s = 0.f;
            #pragma unroll
            for (int r = 0; r < 16; ++r) {
                float v = best[p][r];
                v = fminf(v, smem[(0 * 64 + p * 16 + r) * 64 + lane]);
                v = fminf(v, smem[(1 * 64 + p * 16 + r) * 64 + lane]);
                v = fminf(v, smem[(2 * 64 + p * 16 + r) * 64 + lane]);
                v = fminf(v, __shfl_xor(v, 1,  64));
                v = fminf(v, __shfl_xor(v, 2,  64));
                v = fminf(v, __shfl_xor(v, 4,  64));
                v = fminf(v, __shfl_xor(v, 8,  64));
                v = fminf(v, __shfl_xor(v, 16, 64));
                s += v;                       // 16 row-mins of this k-half
            }
            bsum += s + __shfl_xor(s, 32, 64);  // + other k-half's 16 rows
        }
        if (lane == 0) {
            const float scale = 100.0f * 0.5f / ((float)B_DIM * (float)N_DIM);
            atomicAdd(out, bsum * scale);
        }
    }
}

// Reduce col partials: min over 64 y-blocks per (b,m), sum, atomicAdd.
__global__ __launch_bounds__(256) void chamfer_colreduce(
    const float* __restrict__ colpart, float* __restrict__ out)
{
    const int idx = blockIdx.x * 256 + threadIdx.x;  // (b*8192 + m)
    const int b = idx >> 13, m = idx & (N_DIM - 1);
    const float* base = colpart + (size_t)b * 64 * N_DIM + m;
    float v0 = 1e30f, v1 = 1e30f, v2 = 1e30f, v3 = 1e30f;
    #pragma unroll
    for (int y = 0; y < 64; y += 4) {
        v0 = fminf(v0, base[(size_t)(y + 0) * N_DIM]);
        v1 = fminf(v1, base[(size_t)(y + 1) * N_DIM]);
        v2 = fminf(v2, base[(size_t)(y + 2) * N_DIM]);
        v3 = fminf(v3, base[(size_t)(y + 3) * N_DIM]);
    }
    float v = fminf(fminf(v0, v1), fminf(v2, v3));
    v += __shfl_xor(v, 1,  64);
    v += __shfl_xor(v, 2,  64);
    v += __shfl_xor(v, 4,  64);
    v += __shfl_xor(v, 8,  64);
    v += __shfl_xor(v, 16, 64);
    v += __shfl_xor(v, 32, 64);
    __shared__ float ws4[4];
    const int w = threadIdx.x >> 6, lane = threadIdx.x & 63;
    if (lane == 0) ws4[w] = v;
    __syncthreads();
    if (threadIdx.x == 0) {
        const float scale = 100.0f * 0.5f / ((float)B_DIM * (float)N_DIM);
        atomicAdd(out, (ws4[0] + ws4[1] + ws4[2] + ws4[3]) * scale);
    }
}

// ---------------- fallback path (R19, proven 92.8us) ----------------------
__global__ __launch_bounds__(256) void fb_prep(
    const float* __restrict__ pred, const float* __restrict__ gt,
    unsigned short* __restrict__ bpack, float* __restrict__ out)
{
    const int i   = blockIdx.x * 256 + threadIdx.x;
    if (i == 0) out[0] = 0.0f;
    const int dir = i >> 16;
    const int bm  = i & 0xFFFF;
    const float* dst = dir ? pred : gt;
    const float x = dst[3*bm+0], y = dst[3*bm+1], z = dst[3*bm+2];
    const unsigned short hx = bf16_rne(x), hy = bf16_rne(y), hz = bf16_rne(z);
    const unsigned short lx = bf16_rne(x - bf16f(hx));
    const unsigned short ly = bf16_rne(y - bf16f(hy));
    const unsigned short lz = bf16_rne(z - bf16f(hz));
    const float gn = x*x + y*y + z*z;
    const unsigned short gnh = bf16_rne(gn), gnl = bf16_rne(gn - bf16f(gnh));
    const unsigned short one = 0x3F80;
    const int b  = bm >> 13, m = bm & (N_DIM - 1);
    const int mt = m >> 5,   c = m & 31;
    const int dirb = (dir << 3) | b;
    unsigned short* p0 = bpack + ((size_t)(dirb * MT + mt) * 64 + c) * 8;
    unsigned short* p1 = p0 + 32 * 8;
    bf16x8 h0 = {(short)hx,(short)hy,(short)hz,(short)lx,(short)ly,(short)lz,(short)hx,(short)hy};
    bf16x8 h1 = {(short)hz,(short)one,(short)one,(short)gnh,(short)gnl,0,0,0};
    *(bf16x8*)p0 = h0;
    *(bf16x8*)p1 = h1;
}

__global__ __launch_bounds__(BLOCK, 2) void fb_partial(
    const float* __restrict__ pred, const float* __restrict__ gt,
    const bf16x8* __restrict__ bpack, float* __restrict__ out)
{
    __shared__ float cbuf[PPW * 16 * 128];
    __shared__ float wsum[2];
    const int dirb = blockIdx.x;
    const int dir  = dirb >> 3, b = dirb & 7;
    const int w    = threadIdx.x >> 6, lane = threadIdx.x & 63;
    const int halfk = lane >> 5,  col = lane & 31;
    const int nsub = w & 1;
    const int mh   = w >> 1;
    const float* src  = dir ? gt : pred;
    const float* srcb = src + (size_t)b * N_DIM * 3;
    bf16x8 afrag[PPW];
    #pragma unroll
    for (int p = 0; p < PPW; ++p) {
        const int n = (blockIdx.y * 8 + nsub * PPW + p) * 32 + col;
        const float x = srcb[3*n+0], y = srcb[3*n+1], z = srcb[3*n+2];
        const float ax = -2.f*x, ay = -2.f*y, az = -2.f*z;
        const unsigned short ahx = bf16_rne(ax), ahy = bf16_rne(ay), ahz = bf16_rne(az);
        const unsigned short alx = bf16_rne(ax - bf16f(ahx));
        const unsigned short aly = bf16_rne(ay - bf16f(ahy));
        const unsigned short alz = bf16_rne(az - bf16f(ahz));
        const float pn = x*x + y*y + z*z;
        const unsigned short pnh = bf16_rne(pn), pnl = bf16_rne(pn - bf16f(pnh));
        const unsigned short one = 0x3F80;
        bf16x8 a0 = {(short)ahx,(short)ahy,(short)ahz,(short)ahx,(short)ahy,(short)ahz,(short)alx,(short)aly};
        bf16x8 a1 = {(short)alz,(short)pnh,(short)pnl,(short)one,(short)one,0,0,0};
        afrag[p] = (halfk == 0) ? a0 : a1;
    }
    float best[PPW][16];
    #pragma unroll
    for (int p = 0; p < PPW; ++p)
        #pragma unroll
        for (int r = 0; r < 16; ++r) best[p][r] = 1e30f;
    const bf16x8* bw = bpack + (size_t)dirb * (MT * 64) + (size_t)(mh * 128) * 64 + lane;
#define FOLD(c0_, c1_) { \
        _Pragma("unroll") \
        for (int p = 0; p < PPW; ++p) { \
            f32x16 d0, d1; \
            asm volatile( \
                "v_mfma_f32_32x32x16_bf16 %0, %2, %3, 0\n\t" \
                "v_mfma_f32_32x32x16_bf16 %1, %2, %4, 0\n\t" \
                "s_nop 7\n\t" \
                "s_nop 3" \
                : "=&v"(d0), "=&v"(d1) \
                : "v"(afrag[p]), "v"(c0_), "v"(c1_)); \
            __builtin_amdgcn_sched_barrier(0x34); \
            _Pragma("unroll") \
            for (int r = 0; r < 16; ++r) \
                asm("v_min3_f32 %0, %0, %1, %2" \
                    : "+v"(best[p][r]) : "v"(d0[r]), "v"(d1[r])); \
        } \
    }
    bf16x8 cA0 = bw[0],   cA1 = bw[64];
    bf16x8 cB0 = bw[128], cB1 = bw[192];
    bf16x8 cC0 = bw[256], cC1 = bw[320];
    bf16x8 cD0 = bw[384], cD1 = bw[448];
    bw += 512;
    for (int t = 0; t < 15; ++t) {
        FOLD(cA0, cA1);  cA0 = bw[0];   cA1 = bw[64];
        FOLD(cB0, cB1);  cB0 = bw[128]; cB1 = bw[192];
        FOLD(cC0, cC1);  cC0 = bw[256]; cC1 = bw[320];
        FOLD(cD0, cD1);  cD0 = bw[384]; cD1 = bw[448];
        bw += 512;
    }
    FOLD(cA0, cA1);
    FOLD(cB0, cB1);
    FOLD(cC0, cC1);
    FOLD(cD0, cD1);
    if (mh == 1) {
        #pragma unroll
        for (int p = 0; p < PPW; ++p)
            #pragma unroll
            for (int r = 0; r < 16; ++r)
                cbuf[(p * 16 + r) * 128 + nsub * 64 + lane] = best[p][r];
    }
    __syncthreads();
    if (mh == 0) {
        float bsum = 0.f;
        #pragma unroll
        for (int p = 0; p < PPW; ++p) {
            float s = 0.f;
            #pragma unroll
            for (int r = 0; r < 16; ++r) {
                float v = fminf(best[p][r], cbuf[(p * 16 + r) * 128 + nsub * 64 + lane]);
                v = fminf(v, __shfl_xor(v, 1,  64));
                v = fminf(v, __shfl_xor(v, 2,  64));
                v = fminf(v, __shfl_xor(v, 4,  64));
                v = fminf(v, __shfl_xor(v, 8,  64));
                v = fminf(v, __shfl_xor(v, 16, 64));
                s += v;
            }
            bsum += s + __shfl_xor(s, 32, 64);
        }
        if (lane == 0) wsum[nsub] = bsum;
    }
    __syncthreads();
    if (threadIdx.x == 0) {
        const float scale = 100.0f * 0.5f / ((float)B_DIM * (float)N_DIM);
        atomicAdd(out, (wsum[0] + wsum[1]) * scale);
    }
}

extern "C" void kernel_launch(void* const* d_in, const int* in_sizes, int n_in,
                              void* d_out, int out_size, void* d_ws, size_t ws_size,
                              hipStream_t stream) {
    const float* pred = (const float*)d_in[0];
    const float* gt   = (const float*)d_in[1];
    float* out = (float*)d_out;

    const size_t GT_BYTES  = (size_t)2 << 20;                 // 2 MiB gtpack
    const size_t COL_BYTES = (size_t)B_DIM * 64 * N_DIM * 4;  // 16 MiB colpart

    if (ws_size >= GT_BYTES + COL_BYTES) {
        unsigned short* gtpack = (unsigned short*)d_ws;
        float* colpart = (float*)((char*)d_ws + GT_BYTES);
        prep_gt<<<(B_DIM * N_DIM) / 256, 256, 0, stream>>>(gt, gtpack, out);
        dim3 grid(B_DIM, N_DIM / 128);      // 8 x 64 = 512 blocks, 2/CU
        chamfer_main<<<grid, BLOCK, 0, stream>>>(pred, (const bf16x8*)gtpack,
                                                 colpart, out);
        chamfer_colreduce<<<(B_DIM * N_DIM) / 256, 256, 0, stream>>>(colpart, out);
    } else {
        unsigned short* bpack = (unsigned short*)d_ws;        // 4 MiB
        fb_prep<<<(2 * B_DIM * N_DIM) / 256, 256, 0, stream>>>(pred, gt, bpack, out);
        dim3 grid(16, N_DIM / 256);
        fb_partial<<<grid, BLOCK, 0, stream>>>(pred, gt, (const bf16x8*)bpack, out);
    }
}

// Round 15
// 93.689 us; speedup vs baseline: 1.1157x; 1.1157x over previous
//
#include <hip/hip_runtime.h>

// Chamfer distance: B=8, N=M=8192, D=3, fp32, via bf16 split-precision MFMA.
// R22: Unifying theory of 6 scheduling nulls (R15-R21): all waves sharing a
//   dirb slice read the SAME addresses in lockstep -> per XCD, ~64 waves'
//   phase-loads target one 2KB region -> single L2 channel serializes
//   ~64KB/phase (~500 cyc) while others idle. Explains: occupancy x2.2
//   flat (more waves = more conflict), traffic /2 flat (same requesters),
//   MFMA batching flat, depth-3 prefetch flat (throughput- not latency-
//   limited). Also identified: the ~44us fillBufferAligned (harness ws
//   re-poison) is the bulk of the "fixed overhead"; one-pass's 3rd node
//   (colreduce ~12us) ate its gain -> revert to two-pass R19.
//   Fix (ONE change to R19): per-block staggered start. ms = yb & 15;
//   iterate the 16 macro-chunks (512 frags each) cyclically from ms.
//   Concurrent waves hit 16 distinct regions -> ~16 L2 channels parallel
//   -> per-phase service ~30-50 cyc. Min-fold is order-independent ->
//   identical result. Everything else R19-verbatim (proven 92.8us).

#define B_DIM 8
#define N_DIM 8192
#define MT    (N_DIM / 32)      // 256 m-tiles per (dir,b)
#define BLOCK 256
#define PPW   4                 // n-tiles per wave

typedef short  bf16x8 __attribute__((ext_vector_type(8)));
typedef float  f32x16 __attribute__((ext_vector_type(16)));

__device__ __forceinline__ unsigned short bf16_rne(float f) {
    unsigned int u = __float_as_uint(f);
    u += 0x7fffu + ((u >> 16) & 1u);
    return (unsigned short)(u >> 16);
}
__device__ __forceinline__ float bf16f(unsigned short h) {
    return __uint_as_float(((unsigned int)h) << 16);
}

// Pack B-fragments for both directions. Layout: 16-byte frags indexed
// [dirb][mtile][half][m32] so a wave's 64 lanes read 1024 contiguous bytes.
__global__ __launch_bounds__(256) void chamfer_prep(
    const float* __restrict__ pred, const float* __restrict__ gt,
    unsigned short* __restrict__ bpack, float* __restrict__ out)
{
    const int i   = blockIdx.x * 256 + threadIdx.x;  // 0 .. 2*B*N-1
    if (i == 0) out[0] = 0.0f;
    const int dir = i >> 16;
    const int bm  = i & 0xFFFF;                      // b*N + m
    const float* dst = dir ? pred : gt;
    const float x = dst[3*bm+0], y = dst[3*bm+1], z = dst[3*bm+2];
    const unsigned short hx = bf16_rne(x), hy = bf16_rne(y), hz = bf16_rne(z);
    const unsigned short lx = bf16_rne(x - bf16f(hx));
    const unsigned short ly = bf16_rne(y - bf16f(hy));
    const unsigned short lz = bf16_rne(z - bf16f(hz));
    const float gn = x*x + y*y + z*z;
    const unsigned short gnh = bf16_rne(gn), gnl = bf16_rne(gn - bf16f(gnh));
    const unsigned short one = 0x3F80;

    const int b  = bm >> 13, m = bm & (N_DIM - 1);
    const int mt = m >> 5,   c = m & 31;
    const int dirb = (dir << 3) | b;
    unsigned short* p0 = bpack + ((size_t)(dirb * MT + mt) * 64 + c) * 8;
    unsigned short* p1 = p0 + 32 * 8;
    // half0 = k0..7 : gh(xyz) gl(xyz) gh(x,y) ; half1 = k8..15 : gh(z) 1 1 gnh gnl 0 0 0
    bf16x8 h0 = {(short)hx,(short)hy,(short)hz,(short)lx,(short)ly,(short)lz,(short)hx,(short)hy};
    bf16x8 h1 = {(short)hz,(short)one,(short)one,(short)gnh,(short)gnl,0,0,0};
    *(bf16x8*)p0 = h0;
    *(bf16x8*)p1 = h1;
}

__global__ __launch_bounds__(BLOCK, 2) void chamfer_partial(
    const float* __restrict__ pred, const float* __restrict__ gt,
    const bf16x8* __restrict__ bpack, float* __restrict__ out)
{
    __shared__ float cbuf[PPW * 16 * 128];  // 32 KB combine buffer (epilogue only)
    __shared__ float wsum[2];
    const int dirb = blockIdx.x;            // low grid bits -> XCD = dirb%8
    const int dir  = dirb >> 3, b = dirb & 7;
    const int w    = threadIdx.x >> 6, lane = threadIdx.x & 63;
    const int halfk = lane >> 5,  col = lane & 31;
    const int nsub = w & 1;                 // which n-tile quad
    const int mh   = w >> 1;                // m-half: 0 -> tiles 0..127, 1 -> 128..255

    const float* src  = dir ? gt : pred;
    const float* srcb = src + (size_t)b * N_DIM * 3;

    // A fragments for this wave's PPW n-tiles (row = col, k-half = halfk).
    bf16x8 afrag[PPW];
    #pragma unroll
    for (int p = 0; p < PPW; ++p) {
        const int ntile = blockIdx.y * 8 + nsub * PPW + p;
        const int n = ntile * 32 + col;
        const float x = srcb[3*n+0], y = srcb[3*n+1], z = srcb[3*n+2];
        const float ax = -2.f*x, ay = -2.f*y, az = -2.f*z;
        const unsigned short ahx = bf16_rne(ax), ahy = bf16_rne(ay), ahz = bf16_rne(az);
        const unsigned short alx = bf16_rne(ax - bf16f(ahx));
        const unsigned short aly = bf16_rne(ay - bf16f(ahy));
        const unsigned short alz = bf16_rne(az - bf16f(ahz));
        const float pn = x*x + y*y + z*z;
        const unsigned short pnh = bf16_rne(pn), pnl = bf16_rne(pn - bf16f(pnh));
        const unsigned short one = 0x3F80;
        bf16x8 a0 = {(short)ahx,(short)ahy,(short)ahz,(short)ahx,(short)ahy,(short)ahz,(short)alx,(short)aly};
        bf16x8 a1 = {(short)alz,(short)pnh,(short)pnl,(short)one,(short)one,0,0,0};
        afrag[p] = (halfk == 0) ? a0 : a1;
    }

    float best[PPW][16];
    #pragma unroll
    for (int p = 0; p < PPW; ++p)
        #pragma unroll
        for (int r = 0; r < 16; ++r) best[p][r] = 1e30f;

    // This wave's B-fragment stream: 128 m-tiles, 1 KB (wave) per tile,
    // coalesced dwordx4 per lane. 16 macro-chunks of 512 frags (4 pairs).
    const bf16x8* bq = bpack + (size_t)dirb * (MT * 64) + (size_t)(mh * 128) * 64 + lane;

    // Per n-tile p: MFMA pair in asm (C = inline 0; s_nop 7+3 in-asm
    // covers the MFMA->VALU read hazard), then per-element asm v_min3 on
    // arch VGPRs. R14/R16/R19-proven correct.
#define FOLD(c0_, c1_) { \
        _Pragma("unroll") \
        for (int p = 0; p < PPW; ++p) { \
            f32x16 d0, d1; \
            asm volatile( \
                "v_mfma_f32_32x32x16_bf16 %0, %2, %3, 0\n\t" \
                "v_mfma_f32_32x32x16_bf16 %1, %2, %4, 0\n\t" \
                "s_nop 7\n\t" \
                "s_nop 3" \
                : "=&v"(d0), "=&v"(d1) \
                : "v"(afrag[p]), "v"(c0_), "v"(c1_)); \
            __builtin_amdgcn_sched_barrier(0x34); \
            _Pragma("unroll") \
            for (int r = 0; r < 16; ++r) \
                asm("v_min3_f32 %0, %0, %1, %2" \
                    : "+v"(best[p][r]) : "v"(d0[r]), "v"(d1[r])); \
        } \
    }

    // Staggered depth-3 rotation: start at macro-chunk ms = yb & 15 and
    // walk the 16 chunks cyclically. Concurrent waves on an XCD hit 16
    // distinct 2KB regions instead of one -> L2 channel parallelism.
    const int ms = blockIdx.y & 15;
    const bf16x8* bw = bq + ms * 512;
    bf16x8 cA0 = bw[0],   cA1 = bw[64];
    bf16x8 cB0 = bw[128], cB1 = bw[192];
    bf16x8 cC0 = bw[256], cC1 = bw[320];
    bf16x8 cD0 = bw[384], cD1 = bw[448];
    for (int t = 1; t < 16; ++t) {
        const bf16x8* nx = bq + ((ms + t) & 15) * 512;
        FOLD(cA0, cA1);  cA0 = nx[0];   cA1 = nx[64];
        FOLD(cB0, cB1);  cB0 = nx[128]; cB1 = nx[192];
        FOLD(cC0, cC1);  cC0 = nx[256]; cC1 = nx[320];
        FOLD(cD0, cD1);  cD0 = nx[384]; cD1 = nx[448];
    }
    FOLD(cA0, cA1);
    FOLD(cB0, cB1);
    FOLD(cC0, cC1);
    FOLD(cD0, cD1);

    // Combine the two m-halves: waves 2,3 export best[] through LDS,
    // waves 0,1 min-combine. Lanes contiguous -> conflict-free.
    if (mh == 1) {
        #pragma unroll
        for (int p = 0; p < PPW; ++p)
            #pragma unroll
            for (int r = 0; r < 16; ++r)
                cbuf[(p * 16 + r) * 128 + nsub * 64 + lane] = best[p][r];
    }
    __syncthreads();
    if (mh == 0) {
        float bsum = 0.f;
        #pragma unroll
        for (int p = 0; p < PPW; ++p) {
            float s = 0.f;
            #pragma unroll
            for (int r = 0; r < 16; ++r) {
                float v = fminf(best[p][r], cbuf[(p * 16 + r) * 128 + nsub * 64 + lane]);
                v = fminf(v, __shfl_xor(v, 1,  64));
                v = fminf(v, __shfl_xor(v, 2,  64));
                v = fminf(v, __shfl_xor(v, 4,  64));
                v = fminf(v, __shfl_xor(v, 8,  64));
                v = fminf(v, __shfl_xor(v, 16, 64));
                s += v;                       // 16 final row-mins of this k-half
            }
            bsum += s + __shfl_xor(s, 32, 64);  // add other k-half's 16 rows
        }
        if (lane == 0) wsum[nsub] = bsum;
    }
    __syncthreads();
    if (threadIdx.x == 0) {
        const float scale = 100.0f * 0.5f / ((float)B_DIM * (float)N_DIM);
        atomicAdd(out, (wsum[0] + wsum[1]) * scale);
    }
}

extern "C" void kernel_launch(void* const* d_in, const int* in_sizes, int n_in,
                              void* d_out, int out_size, void* d_ws, size_t ws_size,
                              hipStream_t stream) {
    const float* pred = (const float*)d_in[0];
    const float* gt   = (const float*)d_in[1];
    float* out = (float*)d_out;
    unsigned short* bpack = (unsigned short*)d_ws;   // 4 MiB

    chamfer_prep<<<(2 * B_DIM * N_DIM) / 256, 256, 0, stream>>>(pred, gt, bpack, out);

    // dirb x n-chunks(256 pts) = 16 x 32 = 512 blocks, 2/CU, 4 indep waves
    dim3 grid(16, N_DIM / 256);
    chamfer_partial<<<grid, BLOCK, 0, stream>>>(pred, gt, (const bf16x8*)bpack, out);
}

// Round 16
// 93.540 us; speedup vs baseline: 1.1174x; 1.0016x over previous
//
#include <hip/hip_runtime.h>

// Chamfer distance: B=8, N=M=8192, D=3, fp32, via bf16 split-precision MFMA.
// R23: R22 (stagger) = 7th scheduling null at 41.5us/31% MfmaUtil. Re-audit:
//   per-SIMD MFMA pipe demand is 13.7us and even ONE wave's FOLD covers 80%
//   of pipe acceptance -> wave-schedule theories cannot explain 3x. But
//   VALUBusy*t = 16.6us vs 6.8us min3 floor = 2.5x VALU inflation = AGPR
//   copy signature. R14's "refutation" was wrong: "+v" doesn't prevent the
//   allocator parking best[] in AGPRs — it satisfies the constraint with
//   accvgpr_read/write COPIES around every min3 asm (2 extra VALU ops per
//   min3 -> VALU becomes the binding pipe at ~17us; MFMA in-phase-stalls
//   to 31%). VGPR_Count (44-84 across rounds, always << ~186 live values)
//   = ARCH-vgpr count only; rest hides in AGPRs. Budget target comes from
//   __launch_bounds__ min-waves: tried (256,4)=scratch-spill, (256,2)=AGPR
//   split; never (256,1) = max allocator freedom (arch cap 256). Our grid
//   is 512 blocks = 2/CU regardless, and 186 regs still fits 2 waves/SIMD.
//   ONE change vs R22: __launch_bounds__(BLOCK, 1) on chamfer_partial.
//   Discriminator: VGPR_Count ~170-220 -> copies gone; <=100 & flat ->
//   theory dead (clean negative).

#define B_DIM 8
#define N_DIM 8192
#define MT    (N_DIM / 32)      // 256 m-tiles per (dir,b)
#define BLOCK 256
#define PPW   4                 // n-tiles per wave

typedef short  bf16x8 __attribute__((ext_vector_type(8)));
typedef float  f32x16 __attribute__((ext_vector_type(16)));

__device__ __forceinline__ unsigned short bf16_rne(float f) {
    unsigned int u = __float_as_uint(f);
    u += 0x7fffu + ((u >> 16) & 1u);
    return (unsigned short)(u >> 16);
}
__device__ __forceinline__ float bf16f(unsigned short h) {
    return __uint_as_float(((unsigned int)h) << 16);
}

// Pack B-fragments for both directions. Layout: 16-byte frags indexed
// [dirb][mtile][half][m32] so a wave's 64 lanes read 1024 contiguous bytes.
__global__ __launch_bounds__(256) void chamfer_prep(
    const float* __restrict__ pred, const float* __restrict__ gt,
    unsigned short* __restrict__ bpack, float* __restrict__ out)
{
    const int i   = blockIdx.x * 256 + threadIdx.x;  // 0 .. 2*B*N-1
    if (i == 0) out[0] = 0.0f;
    const int dir = i >> 16;
    const int bm  = i & 0xFFFF;                      // b*N + m
    const float* dst = dir ? pred : gt;
    const float x = dst[3*bm+0], y = dst[3*bm+1], z = dst[3*bm+2];
    const unsigned short hx = bf16_rne(x), hy = bf16_rne(y), hz = bf16_rne(z);
    const unsigned short lx = bf16_rne(x - bf16f(hx));
    const unsigned short ly = bf16_rne(y - bf16f(hy));
    const unsigned short lz = bf16_rne(z - bf16f(hz));
    const float gn = x*x + y*y + z*z;
    const unsigned short gnh = bf16_rne(gn), gnl = bf16_rne(gn - bf16f(gnh));
    const unsigned short one = 0x3F80;

    const int b  = bm >> 13, m = bm & (N_DIM - 1);
    const int mt = m >> 5,   c = m & 31;
    const int dirb = (dir << 3) | b;
    unsigned short* p0 = bpack + ((size_t)(dirb * MT + mt) * 64 + c) * 8;
    unsigned short* p1 = p0 + 32 * 8;
    // half0 = k0..7 : gh(xyz) gl(xyz) gh(x,y) ; half1 = k8..15 : gh(z) 1 1 gnh gnl 0 0 0
    bf16x8 h0 = {(short)hx,(short)hy,(short)hz,(short)lx,(short)ly,(short)lz,(short)hx,(short)hy};
    bf16x8 h1 = {(short)hz,(short)one,(short)one,(short)gnh,(short)gnl,0,0,0};
    *(bf16x8*)p0 = h0;
    *(bf16x8*)p1 = h1;
}

__global__ __launch_bounds__(BLOCK, 1) void chamfer_partial(
    const float* __restrict__ pred, const float* __restrict__ gt,
    const bf16x8* __restrict__ bpack, float* __restrict__ out)
{
    __shared__ float cbuf[PPW * 16 * 128];  // 32 KB combine buffer (epilogue only)
    __shared__ float wsum[2];
    const int dirb = blockIdx.x;            // low grid bits -> XCD = dirb%8
    const int dir  = dirb >> 3, b = dirb & 7;
    const int w    = threadIdx.x >> 6, lane = threadIdx.x & 63;
    const int halfk = lane >> 5,  col = lane & 31;
    const int nsub = w & 1;                 // which n-tile quad
    const int mh   = w >> 1;                // m-half: 0 -> tiles 0..127, 1 -> 128..255

    const float* src  = dir ? gt : pred;
    const float* srcb = src + (size_t)b * N_DIM * 3;

    // A fragments for this wave's PPW n-tiles (row = col, k-half = halfk).
    bf16x8 afrag[PPW];
    #pragma unroll
    for (int p = 0; p < PPW; ++p) {
        const int ntile = blockIdx.y * 8 + nsub * PPW + p;
        const int n = ntile * 32 + col;
        const float x = srcb[3*n+0], y = srcb[3*n+1], z = srcb[3*n+2];
        const float ax = -2.f*x, ay = -2.f*y, az = -2.f*z;
        const unsigned short ahx = bf16_rne(ax), ahy = bf16_rne(ay), ahz = bf16_rne(az);
        const unsigned short alx = bf16_rne(ax - bf16f(ahx));
        const unsigned short aly = bf16_rne(ay - bf16f(ahy));
        const unsigned short alz = bf16_rne(az - bf16f(ahz));
        const float pn = x*x + y*y + z*z;
        const unsigned short pnh = bf16_rne(pn), pnl = bf16_rne(pn - bf16f(pnh));
        const unsigned short one = 0x3F80;
        bf16x8 a0 = {(short)ahx,(short)ahy,(short)ahz,(short)ahx,(short)ahy,(short)ahz,(short)alx,(short)aly};
        bf16x8 a1 = {(short)alz,(short)pnh,(short)pnl,(short)one,(short)one,0,0,0};
        afrag[p] = (halfk == 0) ? a0 : a1;
    }

    float best[PPW][16];
    #pragma unroll
    for (int p = 0; p < PPW; ++p)
        #pragma unroll
        for (int r = 0; r < 16; ++r) best[p][r] = 1e30f;

    // This wave's B-fragment stream: 128 m-tiles, 1 KB (wave) per tile,
    // coalesced dwordx4 per lane. 16 macro-chunks of 512 frags (4 pairs).
    const bf16x8* bq = bpack + (size_t)dirb * (MT * 64) + (size_t)(mh * 128) * 64 + lane;

    // Per n-tile p: MFMA pair in asm (C = inline 0; s_nop 7+3 in-asm
    // covers the MFMA->VALU read hazard), then per-element asm v_min3 on
    // arch VGPRs. R14/R16/R19-proven correct.
#define FOLD(c0_, c1_) { \
        _Pragma("unroll") \
        for (int p = 0; p < PPW; ++p) { \
            f32x16 d0, d1; \
            asm volatile( \
                "v_mfma_f32_32x32x16_bf16 %0, %2, %3, 0\n\t" \
                "v_mfma_f32_32x32x16_bf16 %1, %2, %4, 0\n\t" \
                "s_nop 7\n\t" \
                "s_nop 3" \
                : "=&v"(d0), "=&v"(d1) \
                : "v"(afrag[p]), "v"(c0_), "v"(c1_)); \
            __builtin_amdgcn_sched_barrier(0x34); \
            _Pragma("unroll") \
            for (int r = 0; r < 16; ++r) \
                asm("v_min3_f32 %0, %0, %1, %2" \
                    : "+v"(best[p][r]) : "v"(d0[r]), "v"(d1[r])); \
        } \
    }

    // Staggered depth-3 rotation: start at macro-chunk ms = yb & 15 and
    // walk the 16 chunks cyclically (L2-spread; proven result-identical).
    const int ms = blockIdx.y & 15;
    const bf16x8* bw = bq + ms * 512;
    bf16x8 cA0 = bw[0],   cA1 = bw[64];
    bf16x8 cB0 = bw[128], cB1 = bw[192];
    bf16x8 cC0 = bw[256], cC1 = bw[320];
    bf16x8 cD0 = bw[384], cD1 = bw[448];
    for (int t = 1; t < 16; ++t) {
        const bf16x8* nx = bq + ((ms + t) & 15) * 512;
        FOLD(cA0, cA1);  cA0 = nx[0];   cA1 = nx[64];
        FOLD(cB0, cB1);  cB0 = nx[128]; cB1 = nx[192];
        FOLD(cC0, cC1);  cC0 = nx[256]; cC1 = nx[320];
        FOLD(cD0, cD1);  cD0 = nx[384]; cD1 = nx[448];
    }
    FOLD(cA0, cA1);
    FOLD(cB0, cB1);
    FOLD(cC0, cC1);
    FOLD(cD0, cD1);

    // Combine the two m-halves: waves 2,3 export best[] through LDS,
    // waves 0,1 min-combine. Lanes contiguous -> conflict-free.
    if (mh == 1) {
        #pragma unroll
        for (int p = 0; p < PPW; ++p)
            #pragma unroll
            for (int r = 0; r < 16; ++r)
                cbuf[(p * 16 + r) * 128 + nsub * 64 + lane] = best[p][r];
    }
    __syncthreads();
    if (mh == 0) {
        float bsum = 0.f;
        #pragma unroll
        for (int p = 0; p < PPW; ++p) {
            float s = 0.f;
            #pragma unroll
            for (int r = 0; r < 16; ++r) {
                float v = fminf(best[p][r], cbuf[(p * 16 + r) * 128 + nsub * 64 + lane]);
                v = fminf(v, __shfl_xor(v, 1,  64));
                v = fminf(v, __shfl_xor(v, 2,  64));
                v = fminf(v, __shfl_xor(v, 4,  64));
                v = fminf(v, __shfl_xor(v, 8,  64));
                v = fminf(v, __shfl_xor(v, 16, 64));
                s += v;                       // 16 final row-mins of this k-half
            }
            bsum += s + __shfl_xor(s, 32, 64);  // add other k-half's 16 rows
        }
        if (lane == 0) wsum[nsub] = bsum;
    }
    __syncthreads();
    if (threadIdx.x == 0) {
        const float scale = 100.0f * 0.5f / ((float)B_DIM * (float)N_DIM);
        atomicAdd(out, (wsum[0] + wsum[1]) * scale);
    }
}

extern "C" void kernel_launch(void* const* d_in, const int* in_sizes, int n_in,
                              void* d_out, int out_size, void* d_ws, size_t ws_size,
                              hipStream_t stream) {
    const float* pred = (const float*)d_in[0];
    const float* gt   = (const float*)d_in[1];
    float* out = (float*)d_out;
    unsigned short* bpack = (unsigned short*)d_ws;   // 4 MiB

    chamfer_prep<<<(2 * B_DIM * N_DIM) / 256, 256, 0, stream>>>(pred, gt, bpack, out);

    // dirb x n-chunks(256 pts) = 16 x 32 = 512 blocks, 2/CU, 4 indep waves
    dim3 grid(16, N_DIM / 256);
    chamfer_partial<<<grid, BLOCK, 0, stream>>>(pred, gt, (const bf16x8*)bpack, out);
}